// Round 7
// baseline (875.781 us; speedup 1.0000x reference)
//
#include <hip/hip_runtime.h>

#define N_NODES 4096
#define HID 64
#define NH (N_NODES * HID)

typedef float f32x4 __attribute__((ext_vector_type(4)));
typedef short s16x8 __attribute__((ext_vector_type(8)));

__device__ __forceinline__ short f2bf(float f) {
    union { float f; unsigned u; } v; v.f = f;
    unsigned r = v.u + 0x7fffu + ((v.u >> 16) & 1u);  // RTNE
    return (short)(r >> 16);
}

// direct global->LDS DMA, 16B per lane; LDS dest = wave-uniform base + lane*16
#define GLOAD_LDS16(g, l) __builtin_amdgcn_global_load_lds( \
    (const __attribute__((address_space(1))) unsigned int*)(g), \
    (__attribute__((address_space(3))) unsigned int*)(l), 16, 0, 0)

// K1: S = h @ w_self (p==8), BT[r][e][m] = (h @ w_rel[r])[m][e] as bf16 (p<8)
__global__ __launch_bounds__(256) void proj_kernel(
    const float* __restrict__ h, const float* __restrict__ w_self_l,
    const float* __restrict__ w_rel_l, float* __restrict__ S,
    short* __restrict__ BT)
{
    __shared__ float hs[64][65];
    __shared__ float wt[64][64];
    const int tid = threadIdx.x;
    const int mb = blockIdx.x;
    const int p = blockIdx.y;
    const float* w = (p < 8) ? (w_rel_l + p * 64 * 64) : w_self_l;

    #pragma unroll
    for (int i = 0; i < 4; ++i) {
        int idx4 = tid + 256 * i;
        int row = idx4 >> 4, c = idx4 & 15;
        float4 v = *((const float4*)(h + (size_t)(mb * 64 + row) * HID) + c);
        hs[row][c * 4 + 0] = v.x; hs[row][c * 4 + 1] = v.y;
        hs[row][c * 4 + 2] = v.z; hs[row][c * 4 + 3] = v.w;
    }
    #pragma unroll
    for (int i = 0; i < 4; ++i) {
        int idx4 = tid + 256 * i;
        ((float4*)wt)[idx4] = ((const float4*)w)[idx4];
    }
    __syncthreads();

    const int m = tid & 63;
    const int eb = (tid >> 6) * 16;   // wave-uniform
    float acc[16];
    #pragma unroll
    for (int j = 0; j < 16; ++j) acc[j] = 0.f;

    #pragma unroll 4
    for (int d = 0; d < 64; ++d) {
        float hv = hs[m][d];
        const float4* wr = (const float4*)&wt[d][eb];
        float4 w0 = wr[0], w1 = wr[1], w2 = wr[2], w3 = wr[3];
        acc[0]  += hv * w0.x; acc[1]  += hv * w0.y; acc[2]  += hv * w0.z; acc[3]  += hv * w0.w;
        acc[4]  += hv * w1.x; acc[5]  += hv * w1.y; acc[6]  += hv * w1.z; acc[7]  += hv * w1.w;
        acc[8]  += hv * w2.x; acc[9]  += hv * w2.y; acc[10] += hv * w2.z; acc[11] += hv * w2.w;
        acc[12] += hv * w3.x; acc[13] += hv * w3.y; acc[14] += hv * w3.z; acc[15] += hv * w3.w;
    }

    if (p < 8) {
        #pragma unroll
        for (int j = 0; j < 16; ++j)
            BT[(size_t)(p * 64 + eb + j) * N_NODES + mb * 64 + m] = f2bf(acc[j]);
    } else {
        #pragma unroll
        for (int j = 0; j < 16; ++j)
            S[(size_t)(mb * 64 + m) * HID + eb + j] = acc[j];
    }
}

// K2: T3-minimum 2-phase MFMA GEMM.
//   - global_load_lds (16B) double-buffered staging: stage(t+1) issued at the
//     TOP of iteration t, single __syncthreads (with its vmcnt(0) drain) AFTER
//     compute(t) -> issue-to-drain spans the whole compute phase. Old version
//     drained immediately after issue (vmcnt(0) before the 2nd barrier),
//     exposing full HBM latency per iteration.
//   - LDS dest must be linear (no padding) -> XOR swizzle, both sides:
//     A (fp32): 32B-pair  p' = p ^ (row&7);  B (bf16): 16B-chunk c' = c ^ (e&7)
//     pre-swizzled on the GLOBAL source addr, same XOR on the LDS read addr.
//     Read banks land on the 8-cyc b128 floor (row term re-enters bank index).
// Accumulation order identical to the previous passing kernel.
__global__ __launch_bounds__(256, 3) void gemm_kernel(
    const float* __restrict__ A, const short* __restrict__ BT,
    float* __restrict__ msg)
{
    __shared__ __attribute__((aligned(16))) float As[2][4096];  // 2 x 64x64 fp32 (32 KB)
    __shared__ __attribute__((aligned(16))) short Bs[2][4096];  // 2 x 64x64 bf16 (16 KB)

    const int tid = threadIdx.x;
    const int gid = blockIdx.x;
    const int r  = gid & 7;          // relation -> XCD (L2 locality for BT)
    const int rb = (gid >> 3) & 63;  // 64-row tile
    const int ks = gid >> 9;         // K-split half (0/1)
    const int wave = tid >> 6, lane = tid & 63;
    const int quad = lane >> 4, l16 = lane & 15;

    const float* Ag = A  + ((size_t)r * N_NODES + rb * 64) * N_NODES + ks * 2048;
    const short* Bg = BT + ((size_t)r * 64) * N_NODES + ks * 2048;

    f32x4 acc[4];
    #pragma unroll
    for (int nb = 0; nb < 4; ++nb) acc[nb] = (f32x4){0.f, 0.f, 0.f, 0.f};

    // stage tile t into buffer b: 4 A-instrs + 2 B-instrs per thread,
    // each wave-instr fills a contiguous 1 KB LDS region.
    auto stage = [&](int b, int t) {
        const int k0 = t * 64;
        #pragma unroll
        for (int j = 0; j < 4; ++j) {               // A: regions 0..15 (4 rows each)
            int region = wave + j * 4;
            int row = region * 4 + (lane >> 4);
            int sc  = lane & 15;                    // LDS 16B-chunk within row
            int gch = ((((sc >> 1) ^ (row & 7)) << 1) | (sc & 1));
            GLOAD_LDS16(Ag + (size_t)row * N_NODES + k0 + gch * 4,
                        &As[b][region * 256]);
        }
        #pragma unroll
        for (int j = 0; j < 2; ++j) {               // B: regions 0..7 (8 rows each)
            int region = wave + j * 4;
            int e  = region * 8 + (lane >> 3);
            int sc = lane & 7;
            int gch = sc ^ (e & 7);
            GLOAD_LDS16(Bg + (size_t)e * N_NODES + k0 + gch * 8,
                        &Bs[b][region * 512]);
        }
    };

    stage(0, 0);
    __syncthreads();                 // drain prologue stage

    for (int t = 0; t < 32; ++t) {
        const int b = t & 1;
        if (t < 31) stage(b ^ 1, t + 1);   // issue early; drained by barrier below

        #pragma unroll
        for (int s = 0; s < 2; ++s) {
            int sp = (s * 4 + quad) ^ (l16 & 7);       // swizzled pair/chunk index
            const f32x4* ap = (const f32x4*)&As[b][(wave * 16 + l16) * 64 + sp * 8];
            f32x4 af0 = ap[0], af1 = ap[1];
            s16x8 af;
            af[0] = f2bf(af0[0]); af[1] = f2bf(af0[1]); af[2] = f2bf(af0[2]); af[3] = f2bf(af0[3]);
            af[4] = f2bf(af1[0]); af[5] = f2bf(af1[1]); af[6] = f2bf(af1[2]); af[7] = f2bf(af1[3]);
            #pragma unroll
            for (int nb = 0; nb < 4; ++nb) {
                s16x8 bfr = *(const s16x8*)&Bs[b][(nb * 16 + l16) * 64 + sp * 8];
                acc[nb] = __builtin_amdgcn_mfma_f32_16x16x32_bf16(af, bfr, acc[nb], 0, 0, 0);
            }
        }
        __syncthreads();             // vmcnt(0) drain lands AFTER compute
    }

    // partial buffer p = r*2 + ks  (disjoint per block together with rb)
    float* mo = msg + ((size_t)(r * 2 + ks)) * NH;
    // C/D layout: col = l16 (+nb*16), row = quad*4 + i (+wave*16 + rb*64)
    #pragma unroll
    for (int nb = 0; nb < 4; ++nb) {
        #pragma unroll
        for (int i = 0; i < 4; ++i) {
            int orow = rb * 64 + wave * 16 + quad * 4 + i;
            mo[(size_t)orow * HID + nb * 16 + l16] = acc[nb][i];
        }
    }
}

// K3: h_out = relu(S + sum of 16 msg partials)   (float4, 256 blocks x 256 thr)
__global__ __launch_bounds__(256) void relu_kernel(
    const float* __restrict__ S, const float* __restrict__ msg, float* __restrict__ hout)
{
    int i = blockIdx.x * 256 + threadIdx.x;   // float4 index, NH/4 total
    float4 s = ((const float4*)S)[i];
    #pragma unroll
    for (int p = 0; p < 16; ++p) {
        float4 m = ((const float4*)(msg + (size_t)p * NH))[i];
        s.x += m.x; s.y += m.y; s.z += m.z; s.w += m.w;
    }
    float4 o;
    o.x = fmaxf(s.x, 0.f); o.y = fmaxf(s.y, 0.f);
    o.z = fmaxf(s.z, 0.f); o.w = fmaxf(s.w, 0.f);
    ((float4*)hout)[i] = o;
}

// K4: gather with pad-row -> 0
__global__ __launch_bounds__(256) void gather_kernel(
    const float* __restrict__ h2, const int* __restrict__ kw, float* __restrict__ out)
{
    int e = blockIdx.x * 256 + threadIdx.x;   // 131072 total
    int ki = e >> 6, d = e & 63;
    int id = kw[ki];
    out[e] = ((unsigned)id < (unsigned)N_NODES) ? h2[(size_t)id * HID + d] : 0.f;
}

extern "C" void kernel_launch(void* const* d_in, const int* in_sizes, int n_in,
                              void* d_out, int out_size, void* d_ws, size_t ws_size,
                              hipStream_t stream) {
    const float* node_embed = (const float*)d_in[0];   // (4097, 64)
    const float* w_self     = (const float*)d_in[1];   // (2, 64, 64)
    const float* w_rel      = (const float*)d_in[2];   // (2, 8, 64, 64)
    const float* rel_adj    = (const float*)d_in[3];   // (8, 4096, 4096)
    const int*   kw         = (const int*)d_in[4];     // (64, 32)
    float* out = (float*)d_out;                        // (64, 32, 64) fp32

    // workspace carve (23 MB)
    float* msg = (float*)d_ws;                       // 16 * NH f32 partials (r x ks)
    float* S   = msg + 16 * NH;                      // NH f32
    float* h1  = S + NH;                             // NH f32
    float* h2  = h1 + NH;                            // NH f32
    short* BT  = (short*)(h2 + NH);                  // 8*64*4096 bf16

    const float* hin = node_embed;   // layer 0 reads rows 0..4095 only
    float* houts[2] = {h1, h2};
    for (int l = 0; l < 2; ++l) {
        proj_kernel<<<dim3(64, 9), 256, 0, stream>>>(
            hin, w_self + (size_t)l * 64 * 64, w_rel + (size_t)l * 8 * 64 * 64, S, BT);
        gemm_kernel<<<1024, 256, 0, stream>>>(rel_adj, BT, msg);
        relu_kernel<<<256, 256, 0, stream>>>(S, msg, houts[l]);
        hin = houts[l];
    }
    gather_kernel<<<512, 256, 0, stream>>>(h2, kw, out);
}

// Round 8
// 820.974 us; speedup vs baseline: 1.0668x; 1.0668x over previous
//
#include <hip/hip_runtime.h>

#define N_NODES 4096
#define HID 64
#define NH (N_NODES * HID)

typedef float f32x4 __attribute__((ext_vector_type(4)));
typedef short s16x4 __attribute__((ext_vector_type(4)));
typedef short s16x8 __attribute__((ext_vector_type(8)));

__device__ __forceinline__ short f2bf(float f) {
    union { float f; unsigned u; } v; v.f = f;
    unsigned r = v.u + 0x7fffu + ((v.u >> 16) & 1u);  // RTNE
    return (short)(r >> 16);
}

// K1: S = h @ w_self (p==8), BT[r][e][m] = (h @ w_rel[r])[m][e] as bf16 (p<8)
__global__ __launch_bounds__(256) void proj_kernel(
    const float* __restrict__ h, const float* __restrict__ w_self_l,
    const float* __restrict__ w_rel_l, float* __restrict__ S,
    short* __restrict__ BT)
{
    __shared__ float hs[64][65];
    __shared__ float wt[64][64];
    const int tid = threadIdx.x;
    const int mb = blockIdx.x;
    const int p = blockIdx.y;
    const float* w = (p < 8) ? (w_rel_l + p * 64 * 64) : w_self_l;

    #pragma unroll
    for (int i = 0; i < 4; ++i) {
        int idx4 = tid + 256 * i;
        int row = idx4 >> 4, c = idx4 & 15;
        float4 v = *((const float4*)(h + (size_t)(mb * 64 + row) * HID) + c);
        hs[row][c * 4 + 0] = v.x; hs[row][c * 4 + 1] = v.y;
        hs[row][c * 4 + 2] = v.z; hs[row][c * 4 + 3] = v.w;
    }
    #pragma unroll
    for (int i = 0; i < 4; ++i) {
        int idx4 = tid + 256 * i;
        ((float4*)wt)[idx4] = ((const float4*)w)[idx4];
    }
    __syncthreads();

    const int m = tid & 63;
    const int eb = (tid >> 6) * 16;   // wave-uniform
    float acc[16];
    #pragma unroll
    for (int j = 0; j < 16; ++j) acc[j] = 0.f;

    #pragma unroll 4
    for (int d = 0; d < 64; ++d) {
        float hv = hs[m][d];
        const float4* wr = (const float4*)&wt[d][eb];
        float4 w0 = wr[0], w1 = wr[1], w2 = wr[2], w3 = wr[3];
        acc[0]  += hv * w0.x; acc[1]  += hv * w0.y; acc[2]  += hv * w0.z; acc[3]  += hv * w0.w;
        acc[4]  += hv * w1.x; acc[5]  += hv * w1.y; acc[6]  += hv * w1.z; acc[7]  += hv * w1.w;
        acc[8]  += hv * w2.x; acc[9]  += hv * w2.y; acc[10] += hv * w2.z; acc[11] += hv * w2.w;
        acc[12] += hv * w3.x; acc[13] += hv * w3.y; acc[14] += hv * w3.z; acc[15] += hv * w3.w;
    }

    if (p < 8) {
        #pragma unroll
        for (int j = 0; j < 16; ++j)
            BT[(size_t)(p * 64 + eb + j) * N_NODES + mb * 64 + m] = f2bf(acc[j]);
    } else {
        #pragma unroll
        for (int j = 0; j < 16; ++j)
            S[(size_t)(mb * 64 + m) * HID + eb + j] = acc[j];
    }
}

// K2: reg-staged MFMA GEMM, bf16 LDS tiles, single raw barrier per iteration.
//   R7 post-mortem: gload_lds forced vmcnt(0)-at-barrier (cross-wave DMA
//   visibility) + 48KB LDS dropped occupancy to 3 blk/CU -> regression.
//   This version: reg-staged loads are consumed by the SAME wave, so barriers
//   only need lgkmcnt(0) (raw s_barrier, no __syncthreads vmcnt drain). The
//   compiler places a counted vmcnt wait at the a_nx USE (ds_write), a full
//   compute-phase + barrier after issue -> loads in flight across the barrier.
//   A converted f2bf at staging (identical numerics: same per-element RTNE,
//   just before LDS instead of after): halves LDS traffic, 36.9KB dbuf ->
//   4 blocks/CU, zero f2bf on the MFMA path, padded 72-short rows are
//   bank-floor with no swizzle.
// Hazards (1 barrier/iter, compute-then-write): buf b read at t was written
// at t-1 before that iter's lgkm+barrier (RAW ok); buf b^1 written at t was
// last read at t-1 compute, separated by the same barrier (WAR ok).
__global__ __launch_bounds__(256, 4) void gemm_kernel(
    const float* __restrict__ A, const short* __restrict__ BT,
    float* __restrict__ msg)
{
    __shared__ __attribute__((aligned(16))) short As[2][64 * 72];  // bf16, 9 16B-slots/row
    __shared__ __attribute__((aligned(16))) short Bs[2][64 * 72];  // 36864 B total

    const int tid = threadIdx.x;
    const int gid = blockIdx.x;
    const int r  = gid & 7;          // relation -> XCD (L2 locality for BT)
    const int rb = (gid >> 3) & 63;  // 64-row tile
    const int ks = gid >> 9;         // K-split half (0/1)
    const int wave = tid >> 6, lane = tid & 63;
    const int quad = lane >> 4, l16 = lane & 15;

    // coalesced staging maps (adjacent lanes contiguous)
    const int rA = tid >> 4, cA = tid & 15;  // A: 16B f32 chunks, 16/row
    const int rB = tid >> 3, cB = tid & 7;   // B: 16B bf16 chunks, 8/row
    const float* Ag = A  + ((size_t)r * N_NODES + rb * 64) * N_NODES + ks * 2048;
    const short* Bg = BT + ((size_t)r * 64) * N_NODES + ks * 2048;

    f32x4 acc[4];
    #pragma unroll
    for (int nb = 0; nb < 4; ++nb) acc[nb] = (f32x4){0.f, 0.f, 0.f, 0.f};

    f32x4 a_nx[4];
    s16x8 b_nx[2];
    auto load_tile = [&](int t) {
        const int k0 = t * 64;
        #pragma unroll
        for (int j = 0; j < 4; ++j)
            a_nx[j] = __builtin_nontemporal_load(
                (const f32x4*)(Ag + (size_t)(rA + 16 * j) * N_NODES + k0 + cA * 4));
        #pragma unroll
        for (int j = 0; j < 2; ++j)
            b_nx[j] = *(const s16x8*)(Bg + (size_t)(rB + 32 * j) * N_NODES + k0 + cB * 8);
    };
    auto write_tile = [&](int b) {
        #pragma unroll
        for (int j = 0; j < 4; ++j) {
            s16x4 av;
            av[0] = f2bf(a_nx[j][0]); av[1] = f2bf(a_nx[j][1]);
            av[2] = f2bf(a_nx[j][2]); av[3] = f2bf(a_nx[j][3]);
            *(s16x4*)&As[b][(rA + 16 * j) * 72 + cA * 4] = av;
        }
        #pragma unroll
        for (int j = 0; j < 2; ++j)
            *(s16x8*)&Bs[b][(rB + 32 * j) * 72 + cB * 8] = b_nx[j];
    };

    load_tile(0);
    write_tile(0);                   // compiler inserts vmcnt wait at use
    load_tile(1);                    // tile 1 in flight across barrier
    asm volatile("s_waitcnt lgkmcnt(0)" ::: "memory");
    __builtin_amdgcn_s_barrier();

    #pragma unroll 2
    for (int t = 0; t < 32; ++t) {
        const int b = t & 1;
        #pragma unroll
        for (int s = 0; s < 2; ++s) {
            s16x8 af = *(const s16x8*)&As[b][(wave * 16 + l16) * 72 + s * 32 + quad * 8];
            #pragma unroll
            for (int nb = 0; nb < 4; ++nb) {
                s16x8 bfr = *(const s16x8*)&Bs[b][(nb * 16 + l16) * 72 + s * 32 + quad * 8];
                acc[nb] = __builtin_amdgcn_mfma_f32_16x16x32_bf16(af, bfr, acc[nb], 0, 0, 0);
            }
        }
        if (t < 31) {
            __builtin_amdgcn_sched_barrier(0);   // keep write phase after compute
            write_tile(b ^ 1);       // vmcnt wait here (issued 1 iter ago)
            if (t < 30) load_tile(t + 2);
            asm volatile("s_waitcnt lgkmcnt(0)" ::: "memory");
            __builtin_amdgcn_s_barrier();        // no vmcnt drain: loads stay in flight
        }
    }

    // partial buffer p = r*2 + ks  (disjoint per block together with rb)
    float* mo = msg + ((size_t)(r * 2 + ks)) * NH;
    // C/D layout: col = l16 (+nb*16), row = quad*4 + i (+wave*16 + rb*64)
    #pragma unroll
    for (int nb = 0; nb < 4; ++nb) {
        #pragma unroll
        for (int i = 0; i < 4; ++i) {
            int orow = rb * 64 + wave * 16 + quad * 4 + i;
            mo[(size_t)orow * HID + nb * 16 + l16] = acc[nb][i];
        }
    }
}

// K3: h_out = relu(S + sum of 16 msg partials)   (float4, 256 blocks x 256 thr)
__global__ __launch_bounds__(256) void relu_kernel(
    const float* __restrict__ S, const float* __restrict__ msg, float* __restrict__ hout)
{
    int i = blockIdx.x * 256 + threadIdx.x;   // float4 index, NH/4 total
    float4 s = ((const float4*)S)[i];
    #pragma unroll
    for (int p = 0; p < 16; ++p) {
        float4 m = ((const float4*)(msg + (size_t)p * NH))[i];
        s.x += m.x; s.y += m.y; s.z += m.z; s.w += m.w;
    }
    float4 o;
    o.x = fmaxf(s.x, 0.f); o.y = fmaxf(s.y, 0.f);
    o.z = fmaxf(s.z, 0.f); o.w = fmaxf(s.w, 0.f);
    ((float4*)hout)[i] = o;
}

// K4: gather with pad-row -> 0
__global__ __launch_bounds__(256) void gather_kernel(
    const float* __restrict__ h2, const int* __restrict__ kw, float* __restrict__ out)
{
    int e = blockIdx.x * 256 + threadIdx.x;   // 131072 total
    int ki = e >> 6, d = e & 63;
    int id = kw[ki];
    out[e] = ((unsigned)id < (unsigned)N_NODES) ? h2[(size_t)id * HID + d] : 0.f;
}

extern "C" void kernel_launch(void* const* d_in, const int* in_sizes, int n_in,
                              void* d_out, int out_size, void* d_ws, size_t ws_size,
                              hipStream_t stream) {
    const float* node_embed = (const float*)d_in[0];   // (4097, 64)
    const float* w_self     = (const float*)d_in[1];   // (2, 64, 64)
    const float* w_rel      = (const float*)d_in[2];   // (2, 8, 64, 64)
    const float* rel_adj    = (const float*)d_in[3];   // (8, 4096, 4096)
    const int*   kw         = (const int*)d_in[4];     // (64, 32)
    float* out = (float*)d_out;                        // (64, 32, 64) fp32

    // workspace carve (23 MB)
    float* msg = (float*)d_ws;                       // 16 * NH f32 partials (r x ks)
    float* S   = msg + 16 * NH;                      // NH f32
    float* h1  = S + NH;                             // NH f32
    float* h2  = h1 + NH;                            // NH f32
    short* BT  = (short*)(h2 + NH);                  // 8*64*4096 bf16

    const float* hin = node_embed;   // layer 0 reads rows 0..4095 only
    float* houts[2] = {h1, h2};
    for (int l = 0; l < 2; ++l) {
        proj_kernel<<<dim3(64, 9), 256, 0, stream>>>(
            hin, w_self + (size_t)l * 64 * 64, w_rel + (size_t)l * 8 * 64 * 64, S, BT);
        gemm_kernel<<<1024, 256, 0, stream>>>(rel_adj, BT, msg);
        relu_kernel<<<256, 256, 0, stream>>>(S, msg, houts[l]);
        hin = houts[l];
    }
    gather_kernel<<<512, 256, 0, stream>>>(h2, kw, out);
}